// Round 3
// baseline (3839.539 us; speedup 1.0000x reference)
//
#include <hip/hip_runtime.h>
#include <hip/hip_fp16.h>
#include <math.h>

#define N 150
#define NP 152
#define HALF 76
#define QUADS 19          // HALF/4
#define PAIRS 38          // HALF/2
#define BLOCK 320
#define ITERS 100
#define WARM 5

#define PI_F 3.14159265358979323846f
#define TWO_PI_F 6.28318530717958647692f
#define EPS_F 1e-16f
// SINKHORN_EPS = 0.05 ; base-2 log domain: K = C/(eps*ln2), result scale eps*ln2
#define EPSLN2 0.03465735902799726f
#define INV_EPSLN2 28.853900817779268f
#define NEGBIG -1e30f

#if __has_builtin(__builtin_amdgcn_exp2f)
#define FEXP2(x) __builtin_amdgcn_exp2f(x)
#else
#define FEXP2(x) exp2f(x)
#endif
#if __has_builtin(__builtin_amdgcn_logf)
#define FLOG2(x) __builtin_amdgcn_logf(x)
#else
#define FLOG2(x) log2f(x)
#endif

__device__ __forceinline__ float blockReduceSum(float v, float* red) {
    for (int o = 32; o > 0; o >>= 1) v += __shfl_down(v, o, 64);
    const int lane = threadIdx.x & 63;
    const int wv = threadIdx.x >> 6;
    __syncthreads();
    if (lane == 0) red[wv] = v;
    __syncthreads();
    return red[0] + red[1] + red[2] + red[3] + red[4];  // 5 waves
}

__global__ __launch_bounds__(BLOCK, 3) void emd_kernel(
    const float* __restrict__ p_recons,
    const float* __restrict__ p_target,
    float* __restrict__ out)
{
    __shared__ float xeta[NP], xphi[NP], yeta[NP], yphi[NP];
    __shared__ float l2a[NP], l2b[NP];
    __shared__ __align__(16) float uu[NP];
    __shared__ __align__(16) float vv[NP];
    __shared__ float red[5];
    // ~5 KB LDS: occupancy limited by VGPRs, not LDS

    const int b = blockIdx.x;
    const int tid = threadIdx.x;

    // ---- coordinate transform (both clouds) ----
    for (int c = 0; c < 2; ++c) {
        const float* P = (c == 0 ? p_recons : p_target) + (size_t)b * (N * 3);
        float px = 0.f, py = 0.f, pz = 0.f;
        if (tid < N) {
            px = P[tid * 3 + 0];
            py = P[tid * 3 + 1];
            pz = P[tid * 3 + 2];
        }
        const float jx = blockReduceSum(px, red);
        const float jy = blockReduceSum(py, red);
        const float jz = blockReduceSum(pz, red);
        const float jpt  = sqrtf(jx * jx + jy * jy + EPS_F);
        const float jphi = atan2f(jy + EPS_F, jx + EPS_F);
        const float jeta = asinhf(jz / (jpt + EPS_F));

        float ptrel = 0.f, erel = 0.f, prel = 0.f;
        if (tid < N) {
            const float pt  = sqrtf(px * px + py * py + EPS_F);
            const float phi = atan2f(py + EPS_F, px + EPS_F);
            const float eta = asinhf(pz / (pt + EPS_F));
            erel = eta - jeta;
            float d = phi - jphi + PI_F;
            d = fmodf(d, TWO_PI_F);            // JAX % is floor-mod
            if (d < 0.f) d += TWO_PI_F;
            prel = d - PI_F;
            ptrel = pt / (jpt + EPS_F);
        }
        const float spt = blockReduceSum(ptrel, red);
        if (tid < N) {
            const float aa = ptrel / (spt + EPS_F);
            if (c == 0) { xeta[tid] = erel; xphi[tid] = prel; l2a[tid] = FLOG2(aa + EPS_F); }
            else        { yeta[tid] = erel; yphi[tid] = prel; l2b[tid] = FLOG2(aa + EPS_F); }
        }
    }
    __syncthreads();

    // ---- build register-resident fp16 -K (row slice + column slice) ----
    const int r = tid >> 1;       // row for u-pass, col for v-pass, row for epilogue
    const int h = tid & 1;        // which 76-wide half this worker owns
    const bool act = (tid < 2 * N);

    __half2 nKu[PAIRS];   // -K[r][h*76+2s], -K[r][h*76+2s+1]
    __half2 nKt[PAIRS];   // -K[h*76+2s][r], -K[h*76+2s+1][r]
    if (act) {
        const float xe = xeta[r], xp = xphi[r];   // row r of x
        const float ye = yeta[r], yp = yphi[r];   // col r of y
        #pragma unroll
        for (int s = 0; s < PAIRS; ++s) {
            const int j0 = h * HALF + 2 * s;
            float k0 = 0.f, k1 = 0.f, q0 = 0.f, q1 = 0.f;
            if (j0 < N) {
                float de = xe - yeta[j0], dp = xp - yphi[j0];
                k0 = sqrtf(de * de + dp * dp + EPS_F) * INV_EPSLN2;
                de = xeta[j0] - ye; dp = xphi[j0] - yp;
                q0 = sqrtf(de * de + dp * dp + EPS_F) * INV_EPSLN2;
            }
            if (j0 + 1 < N) {
                float de = xe - yeta[j0 + 1], dp = xp - yphi[j0 + 1];
                k1 = sqrtf(de * de + dp * dp + EPS_F) * INV_EPSLN2;
                de = xeta[j0 + 1] - ye; dp = xphi[j0 + 1] - yp;
                q1 = sqrtf(de * de + dp * dp + EPS_F) * INV_EPSLN2;
            }
            nKu[s] = __floats2half2_rn(-k0, -k1);
            nKt[s] = __floats2half2_rn(-q0, -q1);
        }
    }
    if (tid < NP) {
        const float z = (tid < N) ? 0.f : NEGBIG;   // pads stay NEGBIG forever
        uu[tid] = z; vv[tid] = z;
    }
    __syncthreads();

    // ---- Sinkhorn: 100 iterations, single-pass LSE with tracked max after warm-up ----
    float mu = 0.f, mv = 0.f;   // per-thread tracked row/col maxes (combined across h)
    for (int it = 0; it < ITERS; ++it) {
        // u-pass
        if (act) {
            const float4* vp = (const float4*)&vv[h * HALF];
            float m;
            if (it < WARM) {
                float mx = -3e38f;
                #pragma unroll
                for (int s = 0; s < QUADS; ++s) {
                    const float4 v4 = vp[s];
                    const float2 a = __half22float2(nKu[2 * s]);
                    const float2 c2 = __half22float2(nKu[2 * s + 1]);
                    mx = fmaxf(fmaxf(mx, v4.x + a.x), v4.y + a.y);
                    mx = fmaxf(fmaxf(mx, v4.z + c2.x), v4.w + c2.y);
                }
                mx = fmaxf(mx, __shfl_xor(mx, 1, 64));
                m = mx;
            } else {
                m = mu;    // prev-iter max: exact LSE offset while gap <= 100
            }
            float s0 = 0.f, s1 = 0.f, s2 = 0.f, s3 = 0.f, mx = -3e38f;
            #pragma unroll
            for (int s = 0; s < QUADS; ++s) {
                const float4 v4 = vp[s];
                const float2 a = __half22float2(nKu[2 * s]);
                const float2 c2 = __half22float2(nKu[2 * s + 1]);
                const float t0 = v4.x + a.x, t1 = v4.y + a.y;
                const float t2 = v4.z + c2.x, t3 = v4.w + c2.y;
                mx = fmaxf(fmaxf(mx, t0), t1);
                mx = fmaxf(fmaxf(mx, t2), t3);
                s0 += FEXP2(fminf(t0 - m, 100.f));
                s1 += FEXP2(fminf(t1 - m, 100.f));
                s2 += FEXP2(fminf(t2 - m, 100.f));
                s3 += FEXP2(fminf(t3 - m, 100.f));
            }
            float ss = (s0 + s1) + (s2 + s3);
            ss += __shfl_xor(ss, 1, 64);
            mx = fmaxf(mx, __shfl_xor(mx, 1, 64));
            mu = mx;
            if (h == 0) uu[r] = l2a[r] - (m + FLOG2(fmaxf(ss, 1e-37f)));
        }
        __syncthreads();
        // v-pass
        if (act) {
            const float4* up = (const float4*)&uu[h * HALF];
            float m;
            if (it < WARM) {
                float mx = -3e38f;
                #pragma unroll
                for (int s = 0; s < QUADS; ++s) {
                    const float4 u4 = up[s];
                    const float2 a = __half22float2(nKt[2 * s]);
                    const float2 c2 = __half22float2(nKt[2 * s + 1]);
                    mx = fmaxf(fmaxf(mx, u4.x + a.x), u4.y + a.y);
                    mx = fmaxf(fmaxf(mx, u4.z + c2.x), u4.w + c2.y);
                }
                mx = fmaxf(mx, __shfl_xor(mx, 1, 64));
                m = mx;
            } else {
                m = mv;
            }
            float s0 = 0.f, s1 = 0.f, s2 = 0.f, s3 = 0.f, mx = -3e38f;
            #pragma unroll
            for (int s = 0; s < QUADS; ++s) {
                const float4 u4 = up[s];
                const float2 a = __half22float2(nKt[2 * s]);
                const float2 c2 = __half22float2(nKt[2 * s + 1]);
                const float t0 = u4.x + a.x, t1 = u4.y + a.y;
                const float t2 = u4.z + c2.x, t3 = u4.w + c2.y;
                mx = fmaxf(fmaxf(mx, t0), t1);
                mx = fmaxf(fmaxf(mx, t2), t3);
                s0 += FEXP2(fminf(t0 - m, 100.f));
                s1 += FEXP2(fminf(t1 - m, 100.f));
                s2 += FEXP2(fminf(t2 - m, 100.f));
                s3 += FEXP2(fminf(t3 - m, 100.f));
            }
            float ss = (s0 + s1) + (s2 + s3);
            ss += __shfl_xor(ss, 1, 64);
            mx = fmaxf(mx, __shfl_xor(mx, 1, 64));
            mv = mx;
            if (h == 0) vv[r] = l2b[r] - (m + FLOG2(fmaxf(ss, 1e-37f)));
        }
        __syncthreads();
    }

    // ---- EMD = eps*ln2 * sum exp2(u+v-K)*K ----
    float acc = 0.f;
    if (act) {
        const float ur = uu[r];
        const float4* vp = (const float4*)&vv[h * HALF];
        #pragma unroll
        for (int s = 0; s < QUADS; ++s) {
            const float4 v4 = vp[s];
            const float2 a = __half22float2(nKu[2 * s]);
            const float2 c2 = __half22float2(nKu[2 * s + 1]);
            acc += FEXP2(fminf(ur + v4.x + a.x, 100.f)) * (-a.x);
            acc += FEXP2(fminf(ur + v4.y + a.y, 100.f)) * (-a.y);
            acc += FEXP2(fminf(ur + v4.z + c2.x, 100.f)) * (-c2.x);
            acc += FEXP2(fminf(ur + v4.w + c2.y, 100.f)) * (-c2.y);
        }
    }
    acc = blockReduceSum(acc, red);
    if (tid == 0) atomicAdd(out, acc * EPSLN2);
}

extern "C" void kernel_launch(void* const* d_in, const int* in_sizes, int n_in,
                              void* d_out, int out_size, void* d_ws, size_t ws_size,
                              hipStream_t stream) {
    const float* pr = (const float*)d_in[0];
    const float* pt = (const float*)d_in[1];
    float* out = (float*)d_out;
    const int B = in_sizes[0] / (N * 3);
    hipMemsetAsync(d_out, 0, sizeof(float) * out_size, stream);
    hipLaunchKernelGGL(emd_kernel, dim3(B), dim3(BLOCK), 0, stream, pr, pt, out);
}

// Round 4
// 2585.408 us; speedup vs baseline: 1.4851x; 1.4851x over previous
//
#include <hip/hip_runtime.h>
#include <math.h>

#define N 150
#define NP 152            // padded for float4 access (2 pad cols/rows)
#define HALF 76
#define QUADS 19          // HALF/4
#define BLOCK 320         // 5 waves; 2 workers per row/col (300 active)
#define ITERS 100
#define WARM 5

#define PI_F 3.14159265358979323846f
#define TWO_PI_F 6.28318530717958647692f
#define EPS_F 1e-16f
// SINKHORN_EPS = 0.05 ; base-2 log domain: K = C/(eps*ln2), result scale eps*ln2
#define EPSLN2 0.03465735902799726f
#define INV_EPSLN2 28.853900817779268f
#define NEGBIG -1e30f

#if __has_builtin(__builtin_amdgcn_exp2f)
#define FEXP2(x) __builtin_amdgcn_exp2f(x)
#else
#define FEXP2(x) exp2f(x)
#endif
#if __has_builtin(__builtin_amdgcn_logf)
#define FLOG2(x) __builtin_amdgcn_logf(x)
#else
#define FLOG2(x) log2f(x)
#endif

__device__ __forceinline__ float blockReduceSum(float v, float* red) {
    for (int o = 32; o > 0; o >>= 1) v += __shfl_down(v, o, 64);
    const int lane = threadIdx.x & 63;
    const int wv = threadIdx.x >> 6;
    __syncthreads();
    if (lane == 0) red[wv] = v;
    __syncthreads();
    return red[0] + red[1] + red[2] + red[3] + red[4];  // 5 waves
}

__global__ __launch_bounds__(BLOCK, 2) void emd_kernel(
    const float* __restrict__ p_recons,
    const float* __restrict__ p_target,
    float* __restrict__ out)
{
    __shared__ float xeta[N], xphi[N], yeta[N], yphi[N];
    __shared__ float l2a[N], l2b[N];
    __shared__ __align__(16) float uu[NP];
    __shared__ __align__(16) float vv[NP];
    __shared__ float red[5];

    const int b = blockIdx.x;
    const int tid = threadIdx.x;

    // ---- coordinate transform (both clouds) ----
    for (int c = 0; c < 2; ++c) {
        const float* P = (c == 0 ? p_recons : p_target) + (size_t)b * (N * 3);
        float px = 0.f, py = 0.f, pz = 0.f;
        if (tid < N) {
            px = P[tid * 3 + 0];
            py = P[tid * 3 + 1];
            pz = P[tid * 3 + 2];
        }
        const float jx = blockReduceSum(px, red);
        const float jy = blockReduceSum(py, red);
        const float jz = blockReduceSum(pz, red);
        const float jpt  = sqrtf(jx * jx + jy * jy + EPS_F);
        const float jphi = atan2f(jy + EPS_F, jx + EPS_F);
        const float jeta = asinhf(jz / (jpt + EPS_F));

        float ptrel = 0.f, erel = 0.f, prel = 0.f;
        if (tid < N) {
            const float pt  = sqrtf(px * px + py * py + EPS_F);
            const float phi = atan2f(py + EPS_F, px + EPS_F);
            const float eta = asinhf(pz / (pt + EPS_F));
            erel = eta - jeta;
            float d = phi - jphi + PI_F;
            d = fmodf(d, TWO_PI_F);            // JAX % is floor-mod
            if (d < 0.f) d += TWO_PI_F;
            prel = d - PI_F;
            ptrel = pt / (jpt + EPS_F);
        }
        const float spt = blockReduceSum(ptrel, red);
        if (tid < N) {
            const float aa = ptrel / (spt + EPS_F);
            if (c == 0) { xeta[tid] = erel; xphi[tid] = prel; l2a[tid] = FLOG2(aa + EPS_F); }
            else        { yeta[tid] = erel; yphi[tid] = prel; l2b[tid] = FLOG2(aa + EPS_F); }
        }
    }
    __syncthreads();

    // ---- register-resident f32 -K slices (row slice for u-pass, col slice for v-pass) ----
    const int r = (tid >> 1) < N ? (tid >> 1) : (N - 1);   // clamped: all threads run uniform code
    const int h = tid & 1;
    const bool writer = (h == 0) && (tid < 2 * N);
    const bool act = (tid < 2 * N);

    float nKu[HALF];   // -K[r][h*76 + s]
    float nKt[HALF];   // -K[h*76 + s][r]
    {
        const float xe = xeta[r], xp = xphi[r];   // row r of x
        const float ye = yeta[r], yp = yphi[r];   // col r of y
        #pragma unroll
        for (int s = 0; s < HALF; ++s) {
            const int j = h * HALF + s;
            float ku = NEGBIG, kt = NEGBIG;       // pads: never contribute
            if (j < N) {
                float de = xe - yeta[j], dp = xp - yphi[j];
                ku = -sqrtf(de * de + dp * dp + EPS_F) * INV_EPSLN2;
                de = xeta[j] - ye; dp = xphi[j] - yp;
                kt = -sqrtf(de * de + dp * dp + EPS_F) * INV_EPSLN2;
            }
            nKu[s] = ku;
            nKt[s] = kt;
        }
    }
    if (tid < NP) {
        const float z = (tid < N) ? 0.f : NEGBIG;   // pads stay NEGBIG forever
        uu[tid] = z; vv[tid] = z;
    }
    __syncthreads();

    // ---- warm-up: two-pass LSE, establish per-row/col maxes ----
    float mu = 0.f, mv = 0.f;
    for (int it = 0; it < WARM; ++it) {
        {   // u-pass
            const float4* vp = (const float4*)&vv[h * HALF];
            float mx = -3e38f;
            #pragma unroll
            for (int s = 0; s < QUADS; ++s) {
                const float4 v4 = vp[s];
                mx = fmaxf(mx, fmaxf(fmaxf(v4.x + nKu[4*s], v4.y + nKu[4*s+1]),
                                     fmaxf(v4.z + nKu[4*s+2], v4.w + nKu[4*s+3])));
            }
            mx = fmaxf(mx, __shfl_xor(mx, 1, 64));
            mu = mx;
            float s0 = 0.f, s1 = 0.f, s2 = 0.f, s3 = 0.f;
            #pragma unroll
            for (int s = 0; s < QUADS; ++s) {
                const float4 v4 = vp[s];
                s0 += FEXP2(v4.x + nKu[4*s]   - mx);
                s1 += FEXP2(v4.y + nKu[4*s+1] - mx);
                s2 += FEXP2(v4.z + nKu[4*s+2] - mx);
                s3 += FEXP2(v4.w + nKu[4*s+3] - mx);
            }
            float ss = (s0 + s1) + (s2 + s3);
            ss += __shfl_xor(ss, 1, 64);
            if (writer) uu[r] = l2a[r] - (mx + FLOG2(fmaxf(ss, 1e-37f)));
        }
        __syncthreads();
        {   // v-pass
            const float4* up = (const float4*)&uu[h * HALF];
            float mx = -3e38f;
            #pragma unroll
            for (int s = 0; s < QUADS; ++s) {
                const float4 u4 = up[s];
                mx = fmaxf(mx, fmaxf(fmaxf(u4.x + nKt[4*s], u4.y + nKt[4*s+1]),
                                     fmaxf(u4.z + nKt[4*s+2], u4.w + nKt[4*s+3])));
            }
            mx = fmaxf(mx, __shfl_xor(mx, 1, 64));
            mv = mx;
            float s0 = 0.f, s1 = 0.f, s2 = 0.f, s3 = 0.f;
            #pragma unroll
            for (int s = 0; s < QUADS; ++s) {
                const float4 u4 = up[s];
                s0 += FEXP2(u4.x + nKt[4*s]   - mx);
                s1 += FEXP2(u4.y + nKt[4*s+1] - mx);
                s2 += FEXP2(u4.z + nKt[4*s+2] - mx);
                s3 += FEXP2(u4.w + nKt[4*s+3] - mx);
            }
            float ss = (s0 + s1) + (s2 + s3);
            ss += __shfl_xor(ss, 1, 64);
            if (writer) vv[r] = l2b[r] - (mx + FLOG2(fmaxf(ss, 1e-37f)));
        }
        __syncthreads();
    }

    // ---- fold frozen maxes into the register K (LSE is offset-exact; clamp guards drift) ----
    #pragma unroll
    for (int s = 0; s < HALF; ++s) nKu[s] -= mu;
    #pragma unroll
    for (int s = 0; s < HALF; ++s) nKt[s] -= mv;

    // ---- steady state: single-pass LSE, 3 VALU + 1 exp2 per element ----
    for (int it = WARM; it < ITERS; ++it) {
        {   // u-pass
            const float4* vp = (const float4*)&vv[h * HALF];
            float s0 = 0.f, s1 = 0.f, s2 = 0.f, s3 = 0.f;
            #pragma unroll
            for (int s = 0; s < QUADS; ++s) {
                const float4 v4 = vp[s];
                s0 += FEXP2(fminf(v4.x + nKu[4*s],   100.f));
                s1 += FEXP2(fminf(v4.y + nKu[4*s+1], 100.f));
                s2 += FEXP2(fminf(v4.z + nKu[4*s+2], 100.f));
                s3 += FEXP2(fminf(v4.w + nKu[4*s+3], 100.f));
            }
            float ss = (s0 + s1) + (s2 + s3);
            ss += __shfl_xor(ss, 1, 64);
            if (writer) uu[r] = l2a[r] - (mu + FLOG2(fmaxf(ss, 1e-37f)));
        }
        __syncthreads();
        {   // v-pass
            const float4* up = (const float4*)&uu[h * HALF];
            float s0 = 0.f, s1 = 0.f, s2 = 0.f, s3 = 0.f;
            #pragma unroll
            for (int s = 0; s < QUADS; ++s) {
                const float4 u4 = up[s];
                s0 += FEXP2(fminf(u4.x + nKt[4*s],   100.f));
                s1 += FEXP2(fminf(u4.y + nKt[4*s+1], 100.f));
                s2 += FEXP2(fminf(u4.z + nKt[4*s+2], 100.f));
                s3 += FEXP2(fminf(u4.w + nKt[4*s+3], 100.f));
            }
            float ss = (s0 + s1) + (s2 + s3);
            ss += __shfl_xor(ss, 1, 64);
            if (writer) vv[r] = l2b[r] - (mv + FLOG2(fmaxf(ss, 1e-37f)));
        }
        __syncthreads();
    }

    // ---- EMD = eps*ln2 * sum exp2(u+v-K)*K ;  nKu[s] == -K - mu  ->  K = -(nKu[s]+mu) ----
    float acc = 0.f;
    {
        const float urm = uu[r] + mu;
        const float4* vp = (const float4*)&vv[h * HALF];
        #pragma unroll
        for (int s = 0; s < QUADS; ++s) {
            const float4 v4 = vp[s];
            const float k0 = -(nKu[4*s]   + mu);
            const float k1 = -(nKu[4*s+1] + mu);
            const float k2 = -(nKu[4*s+2] + mu);
            const float k3 = -(nKu[4*s+3] + mu);
            acc += FEXP2(fminf(urm + v4.x + nKu[4*s],   100.f)) * k0;
            acc += FEXP2(fminf(urm + v4.y + nKu[4*s+1], 100.f)) * k1;
            acc += FEXP2(fminf(urm + v4.z + nKu[4*s+2], 100.f)) * k2;
            acc += FEXP2(fminf(urm + v4.w + nKu[4*s+3], 100.f)) * k3;
        }
    }
    if (!act) acc = 0.f;    // clamped-r threads would duplicate row 149
    acc = blockReduceSum(acc, red);
    if (tid == 0) atomicAdd(out, acc * EPSLN2);
}

extern "C" void kernel_launch(void* const* d_in, const int* in_sizes, int n_in,
                              void* d_out, int out_size, void* d_ws, size_t ws_size,
                              hipStream_t stream) {
    const float* pr = (const float*)d_in[0];
    const float* pt = (const float*)d_in[1];
    float* out = (float*)d_out;
    const int B = in_sizes[0] / (N * 3);
    hipMemsetAsync(d_out, 0, sizeof(float) * out_size, stream);
    hipLaunchKernelGGL(emd_kernel, dim3(B), dim3(BLOCK), 0, stream, pr, pt, out);
}

// Round 5
// 2155.169 us; speedup vs baseline: 1.7815x; 1.1996x over previous
//
#include <hip/hip_runtime.h>
#include <math.h>

#define N 150
#define NP 160            // padded: 4 workers × 40 cols, float4-aligned
#define QUART 40
#define QUADS 10          // QUART/4
#define BLOCK 640         // 10 waves; 4 workers per row (600 active)
#define ITERS 100
#define WARM 5

#define PI_F 3.14159265358979323846f
#define TWO_PI_F 6.28318530717958647692f
#define EPS_F 1e-16f
// SINKHORN_EPS = 0.05 ; base-2 log domain: K = C/(eps*ln2), result scale eps*ln2
#define EPSLN2 0.03465735902799726f
#define INV_EPSLN2 28.853900817779268f
#define NEGBIG -1e30f

#if __has_builtin(__builtin_amdgcn_exp2f)
#define FEXP2(x) __builtin_amdgcn_exp2f(x)
#else
#define FEXP2(x) exp2f(x)
#endif
#if __has_builtin(__builtin_amdgcn_logf)
#define FLOG2(x) __builtin_amdgcn_logf(x)
#else
#define FLOG2(x) log2f(x)
#endif

__device__ __forceinline__ float blockReduceSum(float v, float* red) {
    for (int o = 32; o > 0; o >>= 1) v += __shfl_down(v, o, 64);
    const int lane = threadIdx.x & 63;
    const int wv = threadIdx.x >> 6;
    __syncthreads();
    if (lane == 0) red[wv] = v;
    __syncthreads();
    float s = 0.f;
    #pragma unroll
    for (int i = 0; i < BLOCK / 64; ++i) s += red[i];
    return s;
}

__global__ __launch_bounds__(BLOCK, 2) void emd_kernel(
    const float* __restrict__ p_recons,
    const float* __restrict__ p_target,
    float* __restrict__ out)
{
    __shared__ float xeta[N], xphi[N], yeta[N], yphi[N];
    __shared__ float l2a[N], l2b[N];
    __shared__ __align__(16) float uu[NP];
    __shared__ __align__(16) float vv[NP];
    __shared__ float red[BLOCK / 64];

    const int b = blockIdx.x;
    const int tid = threadIdx.x;

    // ---- coordinate transform (both clouds) ----
    for (int c = 0; c < 2; ++c) {
        const float* P = (c == 0 ? p_recons : p_target) + (size_t)b * (N * 3);
        float px = 0.f, py = 0.f, pz = 0.f;
        if (tid < N) {
            px = P[tid * 3 + 0];
            py = P[tid * 3 + 1];
            pz = P[tid * 3 + 2];
        }
        const float jx = blockReduceSum(px, red);
        const float jy = blockReduceSum(py, red);
        const float jz = blockReduceSum(pz, red);
        const float jpt  = sqrtf(jx * jx + jy * jy + EPS_F);
        const float jphi = atan2f(jy + EPS_F, jx + EPS_F);
        const float jeta = asinhf(jz / (jpt + EPS_F));

        float ptrel = 0.f, erel = 0.f, prel = 0.f;
        if (tid < N) {
            const float pt  = sqrtf(px * px + py * py + EPS_F);
            const float phi = atan2f(py + EPS_F, px + EPS_F);
            const float eta = asinhf(pz / (pt + EPS_F));
            erel = eta - jeta;
            float d = phi - jphi + PI_F;
            d = fmodf(d, TWO_PI_F);            // JAX % is floor-mod
            if (d < 0.f) d += TWO_PI_F;
            prel = d - PI_F;
            ptrel = pt / (jpt + EPS_F);
        }
        const float spt = blockReduceSum(ptrel, red);
        if (tid < N) {
            const float aa = ptrel / (spt + EPS_F);
            if (c == 0) { xeta[tid] = erel; xphi[tid] = prel; l2a[tid] = FLOG2(aa + EPS_F); }
            else        { yeta[tid] = erel; yphi[tid] = prel; l2b[tid] = FLOG2(aa + EPS_F); }
        }
    }
    __syncthreads();

    // ---- register-resident f32 -K slices: 4 workers/row, 40 cols each ----
    const int r = (tid >> 2) < N ? (tid >> 2) : (N - 1);   // clamped for uniform exec
    const int q = tid & 3;
    const bool writer = (q == 0) && ((tid >> 2) < N);
    const bool act = (tid >> 2) < N;

    float nKu[QUART];   // -K[r][q*40 + s]
    float nKt[QUART];   // -K[q*40 + s][r]
    {
        const float xe = xeta[r], xp = xphi[r];   // row r of x
        const float ye = yeta[r], yp = yphi[r];   // col r of y
        #pragma unroll
        for (int s = 0; s < QUART; ++s) {
            const int j = q * QUART + s;
            float ku = NEGBIG, kt = NEGBIG;       // pads never contribute
            if (j < N) {
                float de = xe - yeta[j], dp = xp - yphi[j];
                ku = -sqrtf(de * de + dp * dp + EPS_F) * INV_EPSLN2;
                de = xeta[j] - ye; dp = xphi[j] - yp;
                kt = -sqrtf(de * de + dp * dp + EPS_F) * INV_EPSLN2;
            }
            nKu[s] = ku;
            nKt[s] = kt;
        }
    }
    if (tid < NP) {
        const float z = (tid < N) ? 0.f : NEGBIG;   // pads stay NEGBIG forever
        uu[tid] = z; vv[tid] = z;
    }
    __syncthreads();

    // ---- warm-up: two-pass LSE, establish per-row/col maxes ----
    float mu = 0.f, mv = 0.f;
    for (int it = 0; it < WARM; ++it) {
        {   // u-pass
            const float4* vp = (const float4*)&vv[q * QUART];
            float mx = -3e38f;
            #pragma unroll
            for (int s = 0; s < QUADS; ++s) {
                const float4 v4 = vp[s];
                mx = fmaxf(mx, fmaxf(fmaxf(v4.x + nKu[4*s], v4.y + nKu[4*s+1]),
                                     fmaxf(v4.z + nKu[4*s+2], v4.w + nKu[4*s+3])));
            }
            mx = fmaxf(mx, __shfl_xor(mx, 1, 64));
            mx = fmaxf(mx, __shfl_xor(mx, 2, 64));
            mu = mx;
            float s0 = 0.f, s1 = 0.f, s2 = 0.f, s3 = 0.f;
            #pragma unroll
            for (int s = 0; s < QUADS; ++s) {
                const float4 v4 = vp[s];
                s0 += FEXP2(v4.x + nKu[4*s]   - mx);
                s1 += FEXP2(v4.y + nKu[4*s+1] - mx);
                s2 += FEXP2(v4.z + nKu[4*s+2] - mx);
                s3 += FEXP2(v4.w + nKu[4*s+3] - mx);
            }
            float ss = (s0 + s1) + (s2 + s3);
            ss += __shfl_xor(ss, 1, 64);
            ss += __shfl_xor(ss, 2, 64);
            if (writer) uu[r] = l2a[r] - (mx + FLOG2(fmaxf(ss, 1e-37f)));
        }
        __syncthreads();
        {   // v-pass
            const float4* up = (const float4*)&uu[q * QUART];
            float mx = -3e38f;
            #pragma unroll
            for (int s = 0; s < QUADS; ++s) {
                const float4 u4 = up[s];
                mx = fmaxf(mx, fmaxf(fmaxf(u4.x + nKt[4*s], u4.y + nKt[4*s+1]),
                                     fmaxf(u4.z + nKt[4*s+2], u4.w + nKt[4*s+3])));
            }
            mx = fmaxf(mx, __shfl_xor(mx, 1, 64));
            mx = fmaxf(mx, __shfl_xor(mx, 2, 64));
            mv = mx;
            float s0 = 0.f, s1 = 0.f, s2 = 0.f, s3 = 0.f;
            #pragma unroll
            for (int s = 0; s < QUADS; ++s) {
                const float4 u4 = up[s];
                s0 += FEXP2(u4.x + nKt[4*s]   - mx);
                s1 += FEXP2(u4.y + nKt[4*s+1] - mx);
                s2 += FEXP2(u4.z + nKt[4*s+2] - mx);
                s3 += FEXP2(u4.w + nKt[4*s+3] - mx);
            }
            float ss = (s0 + s1) + (s2 + s3);
            ss += __shfl_xor(ss, 1, 64);
            ss += __shfl_xor(ss, 2, 64);
            if (writer) vv[r] = l2b[r] - (mx + FLOG2(fmaxf(ss, 1e-37f)));
        }
        __syncthreads();
    }

    // ---- fold frozen maxes into register K (offset-exact; clamp guards drift) ----
    #pragma unroll
    for (int s = 0; s < QUART; ++s) nKu[s] -= mu;
    #pragma unroll
    for (int s = 0; s < QUART; ++s) nKt[s] -= mv;

    // ---- steady state: single-pass LSE, 3 VALU + 1 exp2 per element ----
    for (int it = WARM; it < ITERS; ++it) {
        {   // u-pass
            const float4* vp = (const float4*)&vv[q * QUART];
            float s0 = 0.f, s1 = 0.f, s2 = 0.f, s3 = 0.f;
            #pragma unroll
            for (int s = 0; s < QUADS; ++s) {
                const float4 v4 = vp[s];
                s0 += FEXP2(fminf(v4.x + nKu[4*s],   100.f));
                s1 += FEXP2(fminf(v4.y + nKu[4*s+1], 100.f));
                s2 += FEXP2(fminf(v4.z + nKu[4*s+2], 100.f));
                s3 += FEXP2(fminf(v4.w + nKu[4*s+3], 100.f));
            }
            float ss = (s0 + s1) + (s2 + s3);
            ss += __shfl_xor(ss, 1, 64);
            ss += __shfl_xor(ss, 2, 64);
            if (writer) uu[r] = l2a[r] - (mu + FLOG2(fmaxf(ss, 1e-37f)));
        }
        __syncthreads();
        {   // v-pass
            const float4* up = (const float4*)&uu[q * QUART];
            float s0 = 0.f, s1 = 0.f, s2 = 0.f, s3 = 0.f;
            #pragma unroll
            for (int s = 0; s < QUADS; ++s) {
                const float4 u4 = up[s];
                s0 += FEXP2(fminf(u4.x + nKt[4*s],   100.f));
                s1 += FEXP2(fminf(u4.y + nKt[4*s+1], 100.f));
                s2 += FEXP2(fminf(u4.z + nKt[4*s+2], 100.f));
                s3 += FEXP2(fminf(u4.w + nKt[4*s+3], 100.f));
            }
            float ss = (s0 + s1) + (s2 + s3);
            ss += __shfl_xor(ss, 1, 64);
            ss += __shfl_xor(ss, 2, 64);
            if (writer) vv[r] = l2b[r] - (mv + FLOG2(fmaxf(ss, 1e-37f)));
        }
        __syncthreads();
    }

    // ---- EMD = eps*ln2 * sum exp2(u+v-K)*K ;  nKu[s] == -K - mu  ->  K = -(nKu[s]+mu) ----
    float acc = 0.f;
    {
        const float urm = uu[r] + mu;
        const float4* vp = (const float4*)&vv[q * QUART];
        #pragma unroll
        for (int s = 0; s < QUADS; ++s) {
            const float4 v4 = vp[s];
            acc += FEXP2(fminf(urm + v4.x + nKu[4*s],   100.f)) * (-(nKu[4*s]   + mu));
            acc += FEXP2(fminf(urm + v4.y + nKu[4*s+1], 100.f)) * (-(nKu[4*s+1] + mu));
            acc += FEXP2(fminf(urm + v4.z + nKu[4*s+2], 100.f)) * (-(nKu[4*s+2] + mu));
            acc += FEXP2(fminf(urm + v4.w + nKu[4*s+3], 100.f)) * (-(nKu[4*s+3] + mu));
        }
    }
    if (!act) acc = 0.f;    // clamped-r threads would duplicate row 149
    acc = blockReduceSum(acc, red);
    if (tid == 0) atomicAdd(out, acc * EPSLN2);
}

extern "C" void kernel_launch(void* const* d_in, const int* in_sizes, int n_in,
                              void* d_out, int out_size, void* d_ws, size_t ws_size,
                              hipStream_t stream) {
    const float* pr = (const float*)d_in[0];
    const float* pt = (const float*)d_in[1];
    float* out = (float*)d_out;
    const int B = in_sizes[0] / (N * 3);
    hipMemsetAsync(d_out, 0, sizeof(float) * out_size, stream);
    hipLaunchKernelGGL(emd_kernel, dim3(B), dim3(BLOCK), 0, stream, pr, pt, out);
}